// Round 1
// baseline (354.691 us; speedup 1.0000x reference)
//
#include <hip/hip_runtime.h>
#include <hip/hip_bf16.h>

// Triplet loss: mean(relu(|  (a-p)W |^2 - |(a-n)W|^2 + 0.2))
// bias cancels in the distance difference -> never read d_in[4].
//
// Layout notes (gfx950, mfma_f32_16x16x32_bf16):
//   A-operand: lane holds A[m = lane&15][k = (lane>>4)*8 + j], j=0..7  (8 bf16)
//   B-operand (assumed symmetric): lane holds B[k = (lane>>4)*8 + j][n = lane&15]
//   C/D:       lane holds D[row = (lane>>4)*4 + reg][col = lane&15]
// W is pre-packed into B-fragment order so the GEMM's W loads are one
// coalesced short8 (16B) per lane per (chunk, n-tile).

#define KDIM  2304   // 48*48
#define EMBD  128
#define BATCH 8192
#define KCH   72     // 2304 / 32
#define NT    8      // 128 / 16
#define ALPHA 0.2f

typedef __attribute__((ext_vector_type(8))) short short8;
typedef __attribute__((ext_vector_type(4))) float f32x4;

__device__ __forceinline__ unsigned short f2bf(float f) {
    unsigned u = __builtin_bit_cast(unsigned, f);
    u += 0x7FFFu + ((u >> 16) & 1u);       // round-to-nearest-even
    return (unsigned short)(u >> 16);
}

// Pack W[k][n] (fp32, row-major [2304,128]) into bf16 MFMA B-fragment order:
// Wp[((c*8 + t)*64 + l)*8 + j] = bf16( W[c*32 + (l>>4)*8 + j][t*16 + (l&15)] )
__global__ void pack_w_kernel(const float* __restrict__ W,
                              unsigned short* __restrict__ Wp) {
    int tid = blockIdx.x * blockDim.x + threadIdx.x;
    int j = tid & 7;
    int l = (tid >> 3) & 63;
    int t = (tid >> 9) & 7;
    int c = tid >> 12;
    if (c >= KCH) return;
    int k = c * 32 + (l >> 4) * 8 + j;
    int n = t * 16 + (l & 15);
    Wp[tid] = f2bf(W[k * EMBD + n]);
}

__global__ __launch_bounds__(64) void triplet_kernel(
    const float* __restrict__ A, const float* __restrict__ P,
    const float* __restrict__ Ng, const unsigned short* __restrict__ Wp,
    float* __restrict__ out)
{
    const int lane = threadIdx.x;
    const int m    = lane & 15;          // A-operand row within this wave's 16 rows
    const int q    = lane >> 4;          // k-quad
    const size_t rowoff = (size_t)(blockIdx.x * 16 + m) * KDIM + q * 8;

    const f32x4* pa = (const f32x4*)(A  + rowoff);
    const f32x4* pp = (const f32x4*)(P  + rowoff);
    const f32x4* pn = (const f32x4*)(Ng + rowoff);
    const short8* wp = (const short8*)Wp + lane;

    f32x4 aU[NT], aV[NT];
#pragma unroll
    for (int t = 0; t < NT; ++t) {
        aU[t] = (f32x4){0.f, 0.f, 0.f, 0.f};
        aV[t] = (f32x4){0.f, 0.f, 0.f, 0.f};
    }

    for (int c = 0; c < KCH; ++c) {
        f32x4 a0 = pa[c * 8], a1 = pa[c * 8 + 1];
        f32x4 p0 = pp[c * 8], p1 = pp[c * 8 + 1];
        f32x4 n0 = pn[c * 8], n1 = pn[c * 8 + 1];
        f32x4 u0 = a0 - p0, u1 = a1 - p1;   // anchor - pos
        f32x4 v0 = a0 - n0, v1 = a1 - n1;   // anchor - neg
        short8 uf, vf;
#pragma unroll
        for (int i = 0; i < 4; ++i) {
            uf[i]     = (short)f2bf(u0[i]);
            uf[i + 4] = (short)f2bf(u1[i]);
            vf[i]     = (short)f2bf(v0[i]);
            vf[i + 4] = (short)f2bf(v1[i]);
        }
        const short8* wc = wp + (size_t)c * NT * 64;
#pragma unroll
        for (int t = 0; t < NT; ++t) {
            short8 bf = wc[t * 64];
            aU[t] = __builtin_amdgcn_mfma_f32_16x16x32_bf16(uf, bf, aU[t], 0, 0, 0);
            aV[t] = __builtin_amdgcn_mfma_f32_16x16x32_bf16(vf, bf, aV[t], 0, 0, 0);
        }
    }

    // Per-lane partial distance: sum over this lane's column across all 8 n-tiles,
    // for each of its 4 rows (reg index r -> row q*4 + r).
    float du[4] = {0.f, 0.f, 0.f, 0.f};
    float dv[4] = {0.f, 0.f, 0.f, 0.f};
#pragma unroll
    for (int t = 0; t < NT; ++t) {
#pragma unroll
        for (int r = 0; r < 4; ++r) {
            du[r] += aU[t][r] * aU[t][r];
            dv[r] += aV[t][r] * aV[t][r];
        }
    }
    // Reduce across the 16 lanes sharing the same k-quad (xor over bits 0..3).
#pragma unroll
    for (int msk = 1; msk < 16; msk <<= 1) {
#pragma unroll
        for (int r = 0; r < 4; ++r) {
            du[r] += __shfl_xor(du[r], msk, 64);
            dv[r] += __shfl_xor(dv[r], msk, 64);
        }
    }
    // Each lane now has full d_ap/d_an for rows q*4 + r. Loss over those 4 rows:
    float s = 0.f;
#pragma unroll
    for (int r = 0; r < 4; ++r) {
        float l = du[r] - dv[r] + ALPHA;
        s += l > 0.f ? l : 0.f;
    }
    // Sum the 4 quad-groups (values replicated within each 16-lane group).
    s += __shfl_xor(s, 16, 64);
    s += __shfl_xor(s, 32, 64);
    if (lane == 0) atomicAdd(out, s * (1.0f / BATCH));
}

extern "C" void kernel_launch(void* const* d_in, const int* in_sizes, int n_in,
                              void* d_out, int out_size, void* d_ws, size_t ws_size,
                              hipStream_t stream) {
    const float* A  = (const float*)d_in[0];
    const float* P  = (const float*)d_in[1];
    const float* Ng = (const float*)d_in[2];
    const float* W  = (const float*)d_in[3];
    unsigned short* Wp = (unsigned short*)d_ws;   // 72*8*64*8 bf16 = 589,824 B

    hipMemsetAsync(d_out, 0, sizeof(float), stream);

    const int packElems = KCH * NT * 64 * 8;      // 294912
    pack_w_kernel<<<packElems / 256, 256, 0, stream>>>(W, Wp);
    triplet_kernel<<<BATCH / 16, 64, 0, stream>>>(A, P, Ng, Wp, (float*)d_out);
}

// Round 2
// 243.458 us; speedup vs baseline: 1.4569x; 1.4569x over previous
//
#include <hip/hip_runtime.h>
#include <hip/hip_bf16.h>

// Triplet loss: mean(relu(|(a-p)W|^2 - |(a-n)W|^2 + 0.2)); bias cancels.
//
// R2: 8-way K-split per block (512 thr = 8 waves; wave w does K-chunks
// [9w, 9w+9)), partial MFMA C-fragments reduced across waves via LDS
// tree (4 regions -> 2 -> 1, 64 KB). Grid 512 blocks -> 4096 waves
// (16/CU) vs R1's 512 waves (2/CU) which was pure latency-bound
// (Occupancy 5.75%, BW 540 GB/s).
//
// Layout (gfx950, mfma_f32_16x16x32_bf16):
//   A: lane holds A[m=lane&15][k=(lane>>4)*8+j]  (8 bf16)
//   B: lane holds B[k=(lane>>4)*8+j][n=lane&15]
//   C/D: lane holds D[row=(lane>>4)*4+reg][col=lane&15]

#define KDIM  2304   // 48*48
#define EMBD  128
#define BATCH 8192
#define KCH   72     // 2304 / 32
#define NT    8      // 128 / 16
#define NW    8      // waves per block
#define CPW   9      // K-chunks per wave (72/8)
#define ALPHA 0.2f

typedef __attribute__((ext_vector_type(8))) short short8;
typedef __attribute__((ext_vector_type(4))) float f32x4;

__device__ __forceinline__ unsigned short f2bf(float f) {
    unsigned u = __builtin_bit_cast(unsigned, f);
    u += 0x7FFFu + ((u >> 16) & 1u);       // round-to-nearest-even
    return (unsigned short)(u >> 16);
}

// Coalesced-read pack: tid walks W row-major; scatter-write into MFMA
// B-fragment order Wp[((c*8+t)*64+l)*8+j] = bf16(W[k][n]),
// k = c*32 + (l>>4)*8 + j, n = t*16 + (l&15).
__global__ void pack_w_kernel(const float* __restrict__ W,
                              unsigned short* __restrict__ Wp) {
    int tid = blockIdx.x * blockDim.x + threadIdx.x;   // 0 .. 2304*128-1
    int n = tid & 127;
    int k = tid >> 7;
    int c = k >> 5;
    int q = (k >> 3) & 3;
    int j = k & 7;
    int t = n >> 4;
    int l = q * 16 + (n & 15);
    Wp[(size_t)(((c * 8 + t) * 64) + l) * 8 + j] = f2bf(W[tid]);
}

__global__ __launch_bounds__(512, 4) void triplet_kernel(
    const float* __restrict__ A, const float* __restrict__ P,
    const float* __restrict__ Ng, const unsigned short* __restrict__ Wp,
    float* __restrict__ out)
{
    __shared__ float lds[4][2][NT][64][4];   // 65536 B: 4 reduce regions

    const int lane = threadIdx.x & 63;
    const int wave = threadIdx.x >> 6;
    const int m    = lane & 15;
    const int q    = lane >> 4;
    const int c0   = wave * CPW;             // this wave's first K-chunk

    const size_t rowoff = (size_t)(blockIdx.x * 16 + m) * KDIM + q * 8;
    const f32x4* pa = (const f32x4*)(A  + rowoff) + (size_t)c0 * 8;
    const f32x4* pp = (const f32x4*)(P  + rowoff) + (size_t)c0 * 8;
    const f32x4* pn = (const f32x4*)(Ng + rowoff) + (size_t)c0 * 8;
    const short8* wp = (const short8*)Wp + lane + (size_t)c0 * NT * 64;

    f32x4 aU[NT], aV[NT];
#pragma unroll
    for (int t = 0; t < NT; ++t) {
        aU[t] = (f32x4){0.f, 0.f, 0.f, 0.f};
        aV[t] = (f32x4){0.f, 0.f, 0.f, 0.f};
    }

#pragma unroll 3
    for (int c = 0; c < CPW; ++c) {
        f32x4 a0 = pa[c * 8], a1 = pa[c * 8 + 1];
        f32x4 p0 = pp[c * 8], p1 = pp[c * 8 + 1];
        f32x4 n0 = pn[c * 8], n1 = pn[c * 8 + 1];
        f32x4 u0 = a0 - p0, u1 = a1 - p1;
        f32x4 v0 = a0 - n0, v1 = a1 - n1;
        short8 uf, vf;
#pragma unroll
        for (int i = 0; i < 4; ++i) {
            uf[i]     = (short)f2bf(u0[i]);
            uf[i + 4] = (short)f2bf(u1[i]);
            vf[i]     = (short)f2bf(v0[i]);
            vf[i + 4] = (short)f2bf(v1[i]);
        }
        const short8* wc = wp + (size_t)c * NT * 64;
#pragma unroll
        for (int t = 0; t < NT; ++t) {
            short8 bf = wc[t * 64];
            aU[t] = __builtin_amdgcn_mfma_f32_16x16x32_bf16(uf, bf, aU[t], 0, 0, 0);
            aV[t] = __builtin_amdgcn_mfma_f32_16x16x32_bf16(vf, bf, aV[t], 0, 0, 0);
        }
    }

    // ---- cross-wave fragment reduce: 8 -> 4 -> 2 -> 1 (wave 0 holds sum) ----
#define STORE_FRAGS(r)                                              \
    do {                                                            \
        _Pragma("unroll")                                           \
        for (int t = 0; t < NT; ++t) {                              \
            *(f32x4*)&lds[r][0][t][lane][0] = aU[t];                \
            *(f32x4*)&lds[r][1][t][lane][0] = aV[t];                \
        }                                                           \
    } while (0)
#define ADD_FRAGS(r)                                                \
    do {                                                            \
        _Pragma("unroll")                                           \
        for (int t = 0; t < NT; ++t) {                              \
            aU[t] += *(const f32x4*)&lds[r][0][t][lane][0];         \
            aV[t] += *(const f32x4*)&lds[r][1][t][lane][0];         \
        }                                                           \
    } while (0)

    if (wave >= 4) STORE_FRAGS(wave - 4);
    __syncthreads();
    if (wave < 4) ADD_FRAGS(wave);
    __syncthreads();
    if (wave == 2 || wave == 3) STORE_FRAGS(wave - 2);
    __syncthreads();
    if (wave < 2) ADD_FRAGS(wave);
    __syncthreads();
    if (wave == 1) STORE_FRAGS(0);
    __syncthreads();

    if (wave == 0) {
        ADD_FRAGS(0);
        float du[4] = {0.f, 0.f, 0.f, 0.f};
        float dv[4] = {0.f, 0.f, 0.f, 0.f};
#pragma unroll
        for (int t = 0; t < NT; ++t) {
#pragma unroll
            for (int r = 0; r < 4; ++r) {
                du[r] += aU[t][r] * aU[t][r];
                dv[r] += aV[t][r] * aV[t][r];
            }
        }
#pragma unroll
        for (int msk = 1; msk < 16; msk <<= 1) {
#pragma unroll
            for (int r = 0; r < 4; ++r) {
                du[r] += __shfl_xor(du[r], msk, 64);
                dv[r] += __shfl_xor(dv[r], msk, 64);
            }
        }
        float s = 0.f;
#pragma unroll
        for (int r = 0; r < 4; ++r) {
            float l = du[r] - dv[r] + ALPHA;
            s += l > 0.f ? l : 0.f;
        }
        s += __shfl_xor(s, 16, 64);
        s += __shfl_xor(s, 32, 64);
        if (lane == 0) atomicAdd(out, s * (1.0f / BATCH));
    }
}

extern "C" void kernel_launch(void* const* d_in, const int* in_sizes, int n_in,
                              void* d_out, int out_size, void* d_ws, size_t ws_size,
                              hipStream_t stream) {
    const float* A  = (const float*)d_in[0];
    const float* P  = (const float*)d_in[1];
    const float* Ng = (const float*)d_in[2];
    const float* W  = (const float*)d_in[3];
    unsigned short* Wp = (unsigned short*)d_ws;   // 72*8*64*8 bf16 = 589,824 B

    hipMemsetAsync(d_out, 0, sizeof(float), stream);

    pack_w_kernel<<<(KDIM * EMBD) / 256, 256, 0, stream>>>(W, Wp);
    triplet_kernel<<<BATCH / 16, 512, 0, stream>>>(A, P, Ng, Wp, (float*)d_out);
}